// Round 1
// baseline (1475.052 us; speedup 1.0000x reference)
//
#include <hip/hip_runtime.h>

#define IN_C 128
#define HID_C 128
#define OUT_C 64

// ---------------------------------------------------------------- utilities

__global__ void zero_kernel(int* __restrict__ p, int n) {
    int i = blockIdx.x * blockDim.x + threadIdx.x;
    if (i < n) p[i] = 0;
}

// histogram of src (out-degree) and dst (in-degree)
__global__ void degree_kernel(const int* __restrict__ src, const int* __restrict__ dst,
                              int* __restrict__ cnt_out, int* __restrict__ cnt_in, int E) {
    for (int i = blockIdx.x * blockDim.x + threadIdx.x; i < E; i += gridDim.x * blockDim.x) {
        atomicAdd(&cnt_out[src[i]], 1);
        atomicAdd(&cnt_in[dst[i]], 1);
    }
}

// single-block exclusive scan of cnt_in -> row_start / cursor, plus inv-sqrt degrees.
__global__ __launch_bounds__(1024)
void scan_kernel(const int* __restrict__ cnt_in, const int* __restrict__ cnt_out,
                 int* __restrict__ row_start, int* __restrict__ cursor,
                 float* __restrict__ iso, float* __restrict__ isi, int N) {
    __shared__ int ssum[1024];
    const int t = threadIdx.x;
    const int CHUNK = (N + 1023) >> 10;
    int lo = t * CHUNK;
    int hi = lo + CHUNK;
    if (lo > N) lo = N;
    if (hi > N) hi = N;

    int s = 0;
    for (int i = lo; i < hi; ++i) s += cnt_in[i];
    ssum[t] = s;
    __syncthreads();
    // Hillis-Steele inclusive scan over 1024 partials
    for (int off = 1; off < 1024; off <<= 1) {
        int v = (t >= off) ? ssum[t - off] : 0;
        __syncthreads();
        ssum[t] += v;
        __syncthreads();
    }
    int run = (t == 0) ? 0 : ssum[t - 1];
    for (int i = lo; i < hi; ++i) {
        row_start[i] = run;
        cursor[i]    = run;
        run += cnt_in[i];
        int di = cnt_in[i]  < 1 ? 1 : cnt_in[i];
        int dd = cnt_out[i] < 1 ? 1 : cnt_out[i];
        isi[i] = rsqrtf((float)di);
        iso[i] = rsqrtf((float)dd);
    }
    if (t == 1023) row_start[N] = ssum[1023];
}

// bucket edges by dst: csr_src[row_start[dst]..] = src
__global__ void fill_kernel(const int* __restrict__ src, const int* __restrict__ dst,
                            int* __restrict__ cursor, int* __restrict__ csr_src, int E) {
    for (int i = blockIdx.x * blockDim.x + threadIdx.x; i < E; i += gridDim.x * blockDim.x) {
        int p = atomicAdd(&cursor[dst[i]], 1);
        csr_src[p] = src[i];
    }
}

// ---------------------------------------------------------------- GEMM
// H[N x C] = (X[N x 128] * iso[:,None]) @ W[128 x C]
// tile: 128 rows x C cols, whole K=128. W + padded-X staged in dynamic LDS.
template <int C>
__global__ __launch_bounds__(256)
void gemm_kernel(const float* __restrict__ X, const float* __restrict__ W,
                 const float* __restrict__ iso, float* __restrict__ H, int N) {
    extern __shared__ float lds[];
    float* Ws = lds;               // 128*C
    float* Xs = lds + 128 * C;     // 128 rows * PAD
    const int PAD = 130;           // rows 8 apart -> +16 banks (2-way, free)
    const int t = threadIdx.x;
    const int row0 = blockIdx.x * 128;

    // stage W
    for (int i = t * 4; i < 128 * C; i += 256 * 4) {
        *(float4*)(Ws + i) = *(const float4*)(W + i);
    }
    // stage X, scaled by iso (128 rows x 32 float4-chunks)
    for (int i = t; i < 128 * 32; i += 256) {
        int r  = i >> 5;
        int kv = (i & 31) << 2;
        int gr = row0 + r;
        if (gr >= N) gr = N - 1;           // clamp (dup row, never stored)
        float sc = iso[gr];
        float4 x = *(const float4*)(X + (size_t)gr * 128 + kv);
        float* d = Xs + r * PAD + kv;
        d[0] = x.x * sc; d[1] = x.y * sc; d[2] = x.z * sc; d[3] = x.w * sc;
    }
    __syncthreads();

    const int CPT = C / 16;                // cols per thread: 8 (C=128) or 4 (C=64)
    const int tc = t & 15, tr = t >> 4;
    const int r0 = tr * 8, c0 = tc * CPT;

    float acc[8][CPT];
#pragma unroll
    for (int i = 0; i < 8; ++i)
#pragma unroll
        for (int j = 0; j < CPT; ++j) acc[i][j] = 0.f;

    for (int k = 0; k < 128; ++k) {
        float a[8];
#pragma unroll
        for (int i = 0; i < 8; ++i) a[i] = Xs[(r0 + i) * PAD + k];
        float b[CPT];
#pragma unroll
        for (int j = 0; j < CPT; ++j) b[j] = Ws[k * C + c0 + j];
#pragma unroll
        for (int i = 0; i < 8; ++i)
#pragma unroll
            for (int j = 0; j < CPT; ++j) acc[i][j] = fmaf(a[i], b[j], acc[i][j]);
    }

#pragma unroll
    for (int i = 0; i < 8; ++i) {
        int gr = row0 + r0 + i;
        if (gr < N) {
#pragma unroll
            for (int j = 0; j < CPT; j += 4) {
                float4 o = make_float4(acc[i][j], acc[i][j + 1], acc[i][j + 2], acc[i][j + 3]);
                *(float4*)(H + (size_t)gr * C + c0 + j) = o;
            }
        }
    }
}

// ---------------------------------------------------------------- aggregation
// one wave per node: out[v] = (sum_{e in CSR[v]} H[src[e]]) * isi[v] + bias
// optional ReLU; FINAL fuses log_softmax across the 64 output columns.
template <int C, bool RELU, bool FINAL>
__global__ __launch_bounds__(256)
void agg_kernel(const float* __restrict__ H, const int* __restrict__ row_start,
                const int* __restrict__ csr_src, const float* __restrict__ isi,
                const float* __restrict__ bias, float* __restrict__ Out, int N) {
    const int wid  = (int)((blockIdx.x * (size_t)blockDim.x + threadIdx.x) >> 6);
    const int lane = threadIdx.x & 63;
    if (wid >= N) return;
    const int rs = row_start[wid];
    const int re = row_start[wid + 1];
    const float sc = isi[wid];

    if (C == 128) {
        float ax = 0.f, ay = 0.f;
        for (int e = rs; e < re; ++e) {
            int s = csr_src[e];
            float2 v = *(const float2*)(H + (size_t)s * 128 + lane * 2);
            ax += v.x; ay += v.y;
        }
        float2 b = *(const float2*)(bias + lane * 2);
        float o0 = ax * sc + b.x;
        float o1 = ay * sc + b.y;
        if (RELU) { o0 = fmaxf(o0, 0.f); o1 = fmaxf(o1, 0.f); }
        float2 o = make_float2(o0, o1);
        *(float2*)(Out + (size_t)wid * 128 + lane * 2) = o;
    } else {
        float a = 0.f;
        for (int e = rs; e < re; ++e) {
            int s = csr_src[e];
            a += H[(size_t)s * 64 + lane];
        }
        float v = a * sc + bias[lane];
        if (FINAL) {
            float m = v;
#pragma unroll
            for (int off = 32; off >= 1; off >>= 1) m = fmaxf(m, __shfl_xor(m, off));
            float ex = expf(v - m);
            float ss = ex;
#pragma unroll
            for (int off = 32; off >= 1; off >>= 1) ss += __shfl_xor(ss, off);
            v = (v - m) - logf(ss);
        }
        if (RELU) v = fmaxf(v, 0.f);
        Out[(size_t)wid * 64 + lane] = v;
    }
}

// ---------------------------------------------------------------- launch

extern "C" void kernel_launch(void* const* d_in, const int* in_sizes, int n_in,
                              void* d_out, int out_size, void* d_ws, size_t ws_size,
                              hipStream_t stream) {
    const float* features = (const float*)d_in[0];
    const int*   src      = (const int*)d_in[1];
    const int*   dst      = (const int*)d_in[2];
    const float* W1       = (const float*)d_in[3];
    const float* b1       = (const float*)d_in[4];
    const float* W2       = (const float*)d_in[5];
    const float* b2       = (const float*)d_in[6];
    const float* W3       = (const float*)d_in[7];
    const float* b3       = (const float*)d_in[8];
    float*       out      = (float*)d_out;

    const int N = in_sizes[0] / IN_C;   // 100000
    const int E = in_sizes[1];          // 1600000

    char* ws = (char*)d_ws;
    const size_t SLOT = 400128;                         // >= (N+1)*4, 128B-aligned
    int*   cnt_out   = (int*)(ws + 0 * SLOT);
    int*   cnt_in    = (int*)(ws + 1 * SLOT);
    int*   row_start = (int*)(ws + 2 * SLOT);
    int*   cursor    = (int*)(ws + 3 * SLOT);
    float* iso       = (float*)(ws + 4 * SLOT);
    float* isi       = (float*)(ws + 5 * SLOT);
    int*   csr       = (int*)(ws + 6 * SLOT);                           // E ints
    float* bufA      = (float*)(ws + 6 * SLOT + 6400000);               // N*128 f32
    float* bufB      = (float*)(ws + 6 * SLOT + 6400000 + 51200000);    // N*128 f32

    // ---- CSR build (per-launch, deterministic work) ----
    const int zn = 2 * (int)(SLOT / 4);
    zero_kernel<<<(zn + 255) / 256, 256, 0, stream>>>(cnt_out, zn);
    degree_kernel<<<1024, 256, 0, stream>>>(src, dst, cnt_out, cnt_in, E);
    scan_kernel<<<1, 1024, 0, stream>>>(cnt_in, cnt_out, row_start, cursor, iso, isi, N);
    fill_kernel<<<1024, 256, 0, stream>>>(src, dst, cursor, csr, E);

    // ---- 3-layer GCN ----
    const int gblocks = (N + 127) / 128;
    const size_t lds128 = (size_t)(128 * 128 + 128 * 130) * sizeof(float); // 129 KiB
    const size_t lds64  = (size_t)(128 * 64  + 128 * 130) * sizeof(float); //  97 KiB
    const int ablocks = (int)(((size_t)N * 64 + 255) / 256);

    // layer 1
    gemm_kernel<128><<<gblocks, 256, lds128, stream>>>(features, W1, iso, bufA, N);
    agg_kernel<128, true, false><<<ablocks, 256, 0, stream>>>(bufA, row_start, csr, isi, b1, bufB, N);
    // layer 2
    gemm_kernel<128><<<gblocks, 256, lds128, stream>>>(bufB, W2, iso, bufA, N);
    agg_kernel<128, true, false><<<ablocks, 256, 0, stream>>>(bufA, row_start, csr, isi, b2, bufB, N);
    // layer 3 + fused log_softmax
    gemm_kernel<64><<<gblocks, 256, lds64, stream>>>(bufB, W3, iso, bufA, N);
    agg_kernel<64, false, true><<<ablocks, 256, 0, stream>>>(bufA, row_start, csr, isi, b3, out, N);
}

// Round 2
// 1048.992 us; speedup vs baseline: 1.4062x; 1.4062x over previous
//
#include <hip/hip_runtime.h>

#define IN_C 128
#define HID_C 128
#define OUT_C 64

// ---------------------------------------------------------------- utilities

__global__ void zero_kernel(int* __restrict__ p, int n) {
    int i = blockIdx.x * blockDim.x + threadIdx.x;
    if (i < n) p[i] = 0;
}

// histogram of src (out-degree) and dst (in-degree)
__global__ void degree_kernel(const int* __restrict__ src, const int* __restrict__ dst,
                              int* __restrict__ cnt_out, int* __restrict__ cnt_in, int E) {
    for (int i = blockIdx.x * blockDim.x + threadIdx.x; i < E; i += gridDim.x * blockDim.x) {
        atomicAdd(&cnt_out[src[i]], 1);
        atomicAdd(&cnt_in[dst[i]], 1);
    }
}

// ---- device-wide exclusive scan of cnt_in (3 passes, 1024 elems/block) ----

__global__ __launch_bounds__(256)
void scan_pass1(const int* __restrict__ cnt_in, int* __restrict__ blocksum, int N) {
    const int b = blockIdx.x, t = threadIdx.x;
    const int base = b * 1024 + t * 4;
    int s = 0;
#pragma unroll
    for (int j = 0; j < 4; ++j) {
        int idx = base + j;
        if (idx < N) s += cnt_in[idx];
    }
#pragma unroll
    for (int off = 32; off >= 1; off >>= 1) s += __shfl_xor(s, off);
    __shared__ int wsum[4];
    if ((t & 63) == 0) wsum[t >> 6] = s;
    __syncthreads();
    if (t == 0) blocksum[b] = wsum[0] + wsum[1] + wsum[2] + wsum[3];
}

// single small block scans the (<=128) block sums
__global__ __launch_bounds__(128)
void scan_pass2(const int* __restrict__ blocksum, int* __restrict__ blockoff,
                int* __restrict__ row_start, int N, int nb) {
    __shared__ int s[128];
    const int t = threadIdx.x;
    int v = (t < nb) ? blocksum[t] : 0;
    s[t] = v;
    __syncthreads();
    for (int off = 1; off < 128; off <<= 1) {
        int x = (t >= off) ? s[t - off] : 0;
        __syncthreads();
        s[t] += x;
        __syncthreads();
    }
    if (t < nb) blockoff[t] = s[t] - v;     // exclusive
    if (t == 127) row_start[N] = s[127];    // total (=E)
}

__global__ __launch_bounds__(256)
void scan_pass3(const int* __restrict__ cnt_in, const int* __restrict__ cnt_out,
                const int* __restrict__ blockoff,
                int* __restrict__ row_start, int* __restrict__ cursor,
                float* __restrict__ iso, float* __restrict__ isi, int N) {
    __shared__ int ssum[256];
    const int b = blockIdx.x, t = threadIdx.x;
    const int base = b * 1024 + t * 4;
    int c[4];
#pragma unroll
    for (int j = 0; j < 4; ++j) {
        int idx = base + j;
        c[j] = (idx < N) ? cnt_in[idx] : 0;
    }
    const int tot = c[0] + c[1] + c[2] + c[3];
    ssum[t] = tot;
    __syncthreads();
    for (int off = 1; off < 256; off <<= 1) {
        int v = (t >= off) ? ssum[t - off] : 0;
        __syncthreads();
        ssum[t] += v;
        __syncthreads();
    }
    int run = blockoff[b] + ssum[t] - tot;  // exclusive prefix for this thread
#pragma unroll
    for (int j = 0; j < 4; ++j) {
        int idx = base + j;
        if (idx < N) {
            row_start[idx] = run;
            cursor[idx]    = run;
            run += c[j];
            int di = c[j] < 1 ? 1 : c[j];
            int co = cnt_out[idx];
            int dd = co < 1 ? 1 : co;
            isi[idx] = rsqrtf((float)di);
            iso[idx] = rsqrtf((float)dd);
        }
    }
}

// bucket edges by dst: csr_src[row_start[dst]..] = src
__global__ void fill_kernel(const int* __restrict__ src, const int* __restrict__ dst,
                            int* __restrict__ cursor, int* __restrict__ csr_src, int E) {
    for (int i = blockIdx.x * blockDim.x + threadIdx.x; i < E; i += gridDim.x * blockDim.x) {
        int p = atomicAdd(&cursor[dst[i]], 1);
        csr_src[p] = src[i];
    }
}

// ---------------------------------------------------------------- GEMM
// H[N x C] = (X[N x 128] * iso[:,None]) @ W[128 x C]
// tile: 128 rows x C cols, whole K=128. W + padded-X staged in dynamic LDS.
template <int C>
__global__ __launch_bounds__(256)
void gemm_kernel(const float* __restrict__ X, const float* __restrict__ W,
                 const float* __restrict__ iso, float* __restrict__ H, int N) {
    extern __shared__ float lds[];
    float* Ws = lds;               // 128*C
    float* Xs = lds + 128 * C;     // 128 rows * PAD
    const int PAD = 130;           // rows 8 apart -> +16 banks (2-way, free)
    const int t = threadIdx.x;
    const int row0 = blockIdx.x * 128;

    // stage W
    for (int i = t * 4; i < 128 * C; i += 256 * 4) {
        *(float4*)(Ws + i) = *(const float4*)(W + i);
    }
    // stage X, scaled by iso (128 rows x 32 float4-chunks)
    for (int i = t; i < 128 * 32; i += 256) {
        int r  = i >> 5;
        int kv = (i & 31) << 2;
        int gr = row0 + r;
        if (gr >= N) gr = N - 1;           // clamp (dup row, never stored)
        float sc = iso[gr];
        float4 x = *(const float4*)(X + (size_t)gr * 128 + kv);
        float* d = Xs + r * PAD + kv;
        d[0] = x.x * sc; d[1] = x.y * sc; d[2] = x.z * sc; d[3] = x.w * sc;
    }
    __syncthreads();

    const int CPT = C / 16;                // cols per thread: 8 (C=128) or 4 (C=64)
    const int tc = t & 15, tr = t >> 4;
    const int r0 = tr * 8, c0 = tc * CPT;

    float acc[8][CPT];
#pragma unroll
    for (int i = 0; i < 8; ++i)
#pragma unroll
        for (int j = 0; j < CPT; ++j) acc[i][j] = 0.f;

    for (int k = 0; k < 128; ++k) {
        float a[8];
#pragma unroll
        for (int i = 0; i < 8; ++i) a[i] = Xs[(r0 + i) * PAD + k];
        float b[CPT];
#pragma unroll
        for (int j = 0; j < CPT; ++j) b[j] = Ws[k * C + c0 + j];
#pragma unroll
        for (int i = 0; i < 8; ++i)
#pragma unroll
            for (int j = 0; j < CPT; ++j) acc[i][j] = fmaf(a[i], b[j], acc[i][j]);
    }

#pragma unroll
    for (int i = 0; i < 8; ++i) {
        int gr = row0 + r0 + i;
        if (gr < N) {
#pragma unroll
            for (int j = 0; j < CPT; j += 4) {
                float4 o = make_float4(acc[i][j], acc[i][j + 1], acc[i][j + 2], acc[i][j + 3]);
                *(float4*)(H + (size_t)gr * C + c0 + j) = o;
            }
        }
    }
}

// ---------------------------------------------------------------- aggregation
// one wave per node: out[v] = (sum_{e in CSR[v]} H[src[e]]) * isi[v] + bias
// optional ReLU; FINAL fuses log_softmax across the 64 output columns.
template <int C, bool RELU, bool FINAL>
__global__ __launch_bounds__(256)
void agg_kernel(const float* __restrict__ H, const int* __restrict__ row_start,
                const int* __restrict__ csr_src, const float* __restrict__ isi,
                const float* __restrict__ bias, float* __restrict__ Out, int N) {
    const int wid  = (int)((blockIdx.x * (size_t)blockDim.x + threadIdx.x) >> 6);
    const int lane = threadIdx.x & 63;
    if (wid >= N) return;
    const int rs = row_start[wid];
    const int re = row_start[wid + 1];
    const float sc = isi[wid];

    if (C == 128) {
        float ax = 0.f, ay = 0.f;
        for (int e = rs; e < re; ++e) {
            int s = csr_src[e];
            float2 v = *(const float2*)(H + (size_t)s * 128 + lane * 2);
            ax += v.x; ay += v.y;
        }
        float2 b = *(const float2*)(bias + lane * 2);
        float o0 = ax * sc + b.x;
        float o1 = ay * sc + b.y;
        if (RELU) { o0 = fmaxf(o0, 0.f); o1 = fmaxf(o1, 0.f); }
        float2 o = make_float2(o0, o1);
        *(float2*)(Out + (size_t)wid * 128 + lane * 2) = o;
    } else {
        float a = 0.f;
        for (int e = rs; e < re; ++e) {
            int s = csr_src[e];
            a += H[(size_t)s * 64 + lane];
        }
        float v = a * sc + bias[lane];
        if (FINAL) {
            float m = v;
#pragma unroll
            for (int off = 32; off >= 1; off >>= 1) m = fmaxf(m, __shfl_xor(m, off));
            float ex = expf(v - m);
            float ss = ex;
#pragma unroll
            for (int off = 32; off >= 1; off >>= 1) ss += __shfl_xor(ss, off);
            v = (v - m) - logf(ss);
        }
        if (RELU) v = fmaxf(v, 0.f);
        Out[(size_t)wid * 64 + lane] = v;
    }
}

// ---------------------------------------------------------------- launch

extern "C" void kernel_launch(void* const* d_in, const int* in_sizes, int n_in,
                              void* d_out, int out_size, void* d_ws, size_t ws_size,
                              hipStream_t stream) {
    const float* features = (const float*)d_in[0];
    const int*   src      = (const int*)d_in[1];
    const int*   dst      = (const int*)d_in[2];
    const float* W1       = (const float*)d_in[3];
    const float* b1       = (const float*)d_in[4];
    const float* W2       = (const float*)d_in[5];
    const float* b2       = (const float*)d_in[6];
    const float* W3       = (const float*)d_in[7];
    const float* b3       = (const float*)d_in[8];
    float*       out      = (float*)d_out;

    const int N = in_sizes[0] / IN_C;   // 100000
    const int E = in_sizes[1];          // 1600000

    char* ws = (char*)d_ws;
    const size_t SLOT = 400128;                         // >= (N+1)*4, 128B-aligned
    int*   cnt_out   = (int*)(ws + 0 * SLOT);
    int*   cnt_in    = (int*)(ws + 1 * SLOT);
    int*   row_start = (int*)(ws + 2 * SLOT);
    int*   cursor    = (int*)(ws + 3 * SLOT);
    float* iso       = (float*)(ws + 4 * SLOT);
    float* isi       = (float*)(ws + 5 * SLOT);
    int*   csr       = (int*)(ws + 6 * SLOT);                           // E ints
    float* bufA      = (float*)(ws + 6 * SLOT + 6400000);               // N*128 f32
    float* bufB      = (float*)(ws + 6 * SLOT + 6400000 + 51200000);    // N*128 f32
    int*   blocksum  = (int*)(ws + 6 * SLOT + 6400000 + 2 * 51200000);  // 128 ints
    int*   blockoff  = blocksum + 128;                                  // 128 ints

    // ---- CSR build (per-launch, deterministic work) ----
    const int zn = 2 * (int)(SLOT / 4);
    const int nb = (N + 1023) / 1024;   // scan blocks (98 for N=100000, <=128)
    zero_kernel<<<(zn + 255) / 256, 256, 0, stream>>>(cnt_out, zn);
    degree_kernel<<<1024, 256, 0, stream>>>(src, dst, cnt_out, cnt_in, E);
    scan_pass1<<<nb, 256, 0, stream>>>(cnt_in, blocksum, N);
    scan_pass2<<<1, 128, 0, stream>>>(blocksum, blockoff, row_start, N, nb);
    scan_pass3<<<nb, 256, 0, stream>>>(cnt_in, cnt_out, blockoff, row_start, cursor, iso, isi, N);
    fill_kernel<<<1024, 256, 0, stream>>>(src, dst, cursor, csr, E);

    // ---- 3-layer GCN ----
    const int gblocks = (N + 127) / 128;
    const size_t lds128 = (size_t)(128 * 128 + 128 * 130) * sizeof(float); // 129 KiB
    const size_t lds64  = (size_t)(128 * 64  + 128 * 130) * sizeof(float); //  97 KiB
    const int ablocks = (int)(((size_t)N * 64 + 255) / 256);

    // layer 1
    gemm_kernel<128><<<gblocks, 256, lds128, stream>>>(features, W1, iso, bufA, N);
    agg_kernel<128, true, false><<<ablocks, 256, 0, stream>>>(bufA, row_start, csr, isi, b1, bufB, N);
    // layer 2
    gemm_kernel<128><<<gblocks, 256, lds128, stream>>>(bufB, W2, iso, bufA, N);
    agg_kernel<128, true, false><<<ablocks, 256, 0, stream>>>(bufA, row_start, csr, isi, b2, bufB, N);
    // layer 3 + fused log_softmax
    gemm_kernel<64><<<gblocks, 256, lds64, stream>>>(bufB, W3, iso, bufA, N);
    agg_kernel<64, false, true><<<ablocks, 256, 0, stream>>>(bufA, row_start, csr, isi, b3, out, N);
}

// Round 3
// 1004.375 us; speedup vs baseline: 1.4686x; 1.0444x over previous
//
#include <hip/hip_runtime.h>
#include <hip/hip_bf16.h>

#define IN_C 128
#define HID_C 128
#define OUT_C 64

typedef unsigned short u16;
typedef unsigned int   u32;

// ---------------------------------------------------------------- utilities

__global__ void zero_kernel(int* __restrict__ p, int n) {
    int i = blockIdx.x * blockDim.x + threadIdx.x;
    if (i < n) p[i] = 0;
}

// histogram of src (out-degree) and dst (in-degree)
__global__ void degree_kernel(const int* __restrict__ src, const int* __restrict__ dst,
                              int* __restrict__ cnt_out, int* __restrict__ cnt_in, int E) {
    for (int i = blockIdx.x * blockDim.x + threadIdx.x; i < E; i += gridDim.x * blockDim.x) {
        atomicAdd(&cnt_out[src[i]], 1);
        atomicAdd(&cnt_in[dst[i]], 1);
    }
}

// ---- device-wide exclusive scan of cnt_in (3 passes, 1024 elems/block) ----

__global__ __launch_bounds__(256)
void scan_pass1(const int* __restrict__ cnt_in, int* __restrict__ blocksum, int N) {
    const int b = blockIdx.x, t = threadIdx.x;
    const int base = b * 1024 + t * 4;
    int s = 0;
#pragma unroll
    for (int j = 0; j < 4; ++j) {
        int idx = base + j;
        if (idx < N) s += cnt_in[idx];
    }
#pragma unroll
    for (int off = 32; off >= 1; off >>= 1) s += __shfl_xor(s, off);
    __shared__ int wsum[4];
    if ((t & 63) == 0) wsum[t >> 6] = s;
    __syncthreads();
    if (t == 0) blocksum[b] = wsum[0] + wsum[1] + wsum[2] + wsum[3];
}

// single small block scans the (<=128) block sums
__global__ __launch_bounds__(128)
void scan_pass2(const int* __restrict__ blocksum, int* __restrict__ blockoff,
                int* __restrict__ row_start, int N, int nb) {
    __shared__ int s[128];
    const int t = threadIdx.x;
    int v = (t < nb) ? blocksum[t] : 0;
    s[t] = v;
    __syncthreads();
    for (int off = 1; off < 128; off <<= 1) {
        int x = (t >= off) ? s[t - off] : 0;
        __syncthreads();
        s[t] += x;
        __syncthreads();
    }
    if (t < nb) blockoff[t] = s[t] - v;     // exclusive
    if (t == 127) row_start[N] = s[127];    // total (=E)
}

__global__ __launch_bounds__(256)
void scan_pass3(const int* __restrict__ cnt_in, const int* __restrict__ cnt_out,
                const int* __restrict__ blockoff,
                int* __restrict__ row_start, int* __restrict__ cursor,
                float* __restrict__ iso, float* __restrict__ isi, int N) {
    __shared__ int ssum[256];
    const int b = blockIdx.x, t = threadIdx.x;
    const int base = b * 1024 + t * 4;
    int c[4];
#pragma unroll
    for (int j = 0; j < 4; ++j) {
        int idx = base + j;
        c[j] = (idx < N) ? cnt_in[idx] : 0;
    }
    const int tot = c[0] + c[1] + c[2] + c[3];
    ssum[t] = tot;
    __syncthreads();
    for (int off = 1; off < 256; off <<= 1) {
        int v = (t >= off) ? ssum[t - off] : 0;
        __syncthreads();
        ssum[t] += v;
        __syncthreads();
    }
    int run = blockoff[b] + ssum[t] - tot;  // exclusive prefix for this thread
#pragma unroll
    for (int j = 0; j < 4; ++j) {
        int idx = base + j;
        if (idx < N) {
            row_start[idx] = run;
            cursor[idx]    = run;
            run += c[j];
            int di = c[j] < 1 ? 1 : c[j];
            int co = cnt_out[idx];
            int dd = co < 1 ? 1 : co;
            isi[idx] = rsqrtf((float)di);
            iso[idx] = rsqrtf((float)dd);
        }
    }
}

// bucket edges by dst: csr_src[row_start[dst]..] = src
__global__ void fill_kernel(const int* __restrict__ src, const int* __restrict__ dst,
                            int* __restrict__ cursor, int* __restrict__ csr_src, int E) {
    for (int i = blockIdx.x * blockDim.x + threadIdx.x; i < E; i += gridDim.x * blockDim.x) {
        int p = atomicAdd(&cursor[dst[i]], 1);
        csr_src[p] = src[i];
    }
}

// ---------------------------------------------------------------- GEMM
// H[N x C] (bf16) = (X[N x 128] * iso[:,None]) @ W[128 x C]
// tile: 128 rows x C cols, whole K=128. W + padded-X staged in dynamic LDS.
template <int C>
__global__ __launch_bounds__(256)
void gemm_kernel(const float* __restrict__ X, const float* __restrict__ W,
                 const float* __restrict__ iso, u16* __restrict__ H, int N) {
    extern __shared__ float lds[];
    float* Ws = lds;               // 128*C
    float* Xs = lds + 128 * C;     // 128 rows * PAD
    const int PAD = 130;           // rows 8 apart -> +16 banks (2-way, free)
    const int t = threadIdx.x;
    const int row0 = blockIdx.x * 128;

    // stage W
    for (int i = t * 4; i < 128 * C; i += 256 * 4) {
        *(float4*)(Ws + i) = *(const float4*)(W + i);
    }
    // stage X, scaled by iso (128 rows x 32 float4-chunks)
    for (int i = t; i < 128 * 32; i += 256) {
        int r  = i >> 5;
        int kv = (i & 31) << 2;
        int gr = row0 + r;
        if (gr >= N) gr = N - 1;           // clamp (dup row, never stored)
        float sc = iso[gr];
        float4 x = *(const float4*)(X + (size_t)gr * 128 + kv);
        float* d = Xs + r * PAD + kv;
        d[0] = x.x * sc; d[1] = x.y * sc; d[2] = x.z * sc; d[3] = x.w * sc;
    }
    __syncthreads();

    const int CPT = C / 16;                // cols per thread: 8 (C=128) or 4 (C=64)
    const int tc = t & 15, tr = t >> 4;
    const int r0 = tr * 8, c0 = tc * CPT;

    float acc[8][CPT];
#pragma unroll
    for (int i = 0; i < 8; ++i)
#pragma unroll
        for (int j = 0; j < CPT; ++j) acc[i][j] = 0.f;

    for (int k = 0; k < 128; ++k) {
        float a[8];
#pragma unroll
        for (int i = 0; i < 8; ++i) a[i] = Xs[(r0 + i) * PAD + k];
        float b[CPT];
#pragma unroll
        for (int j = 0; j < CPT; ++j) b[j] = Ws[k * C + c0 + j];
#pragma unroll
        for (int i = 0; i < 8; ++i)
#pragma unroll
            for (int j = 0; j < CPT; ++j) acc[i][j] = fmaf(a[i], b[j], acc[i][j]);
    }

#pragma unroll
    for (int i = 0; i < 8; ++i) {
        int gr = row0 + r0 + i;
        if (gr < N) {
            alignas(16) u16 u[CPT];
#pragma unroll
            for (int j = 0; j < CPT; ++j) {
                __hip_bfloat16 h = __float2bfloat16(acc[i][j]);   // RNE
                u[j] = *(u16*)&h;
            }
            if (CPT == 8) {
                *(uint4*)(H + (size_t)gr * C + c0) = *(uint4*)u;
            } else {
                *(uint2*)(H + (size_t)gr * C + c0) = *(uint2*)u;
            }
        }
    }
}

// ---------------------------------------------------------------- aggregation
// one wave per node: out[v] = (sum_{e in CSR[v]} Hbf16[src[e]]) * isi[v] + bias
// optional ReLU; FINAL fuses log_softmax across the 64 output columns.
template <int C, bool RELU, bool FINAL>
__global__ __launch_bounds__(256)
void agg_kernel(const u16* __restrict__ H, const int* __restrict__ row_start,
                const int* __restrict__ csr_src, const float* __restrict__ isi,
                const float* __restrict__ bias, float* __restrict__ Out, int N) {
    const int wid  = (int)((blockIdx.x * (size_t)blockDim.x + threadIdx.x) >> 6);
    const int lane = threadIdx.x & 63;
    if (wid >= N) return;
    const int rs = row_start[wid];
    const int re = row_start[wid + 1];
    const float sc = isi[wid];

    if (C == 128) {
        float ax = 0.f, ay = 0.f;
        for (int e = rs; e < re; ++e) {
            int s = csr_src[e];
            u32 v = *(const u32*)(H + (size_t)s * 128 + lane * 2);
            ax += __uint_as_float(v << 16);           // col 2*lane   (low u16)
            ay += __uint_as_float(v & 0xffff0000u);   // col 2*lane+1 (high u16)
        }
        float2 b = *(const float2*)(bias + lane * 2);
        float o0 = ax * sc + b.x;
        float o1 = ay * sc + b.y;
        if (RELU) { o0 = fmaxf(o0, 0.f); o1 = fmaxf(o1, 0.f); }
        float2 o = make_float2(o0, o1);
        *(float2*)(Out + (size_t)wid * 128 + lane * 2) = o;
    } else {
        float a = 0.f;
        for (int e = rs; e < re; ++e) {
            int s = csr_src[e];
            a += __uint_as_float((u32)H[(size_t)s * 64 + lane] << 16);
        }
        float v = a * sc + bias[lane];
        if (FINAL) {
            float m = v;
#pragma unroll
            for (int off = 32; off >= 1; off >>= 1) m = fmaxf(m, __shfl_xor(m, off));
            float ex = expf(v - m);
            float ss = ex;
#pragma unroll
            for (int off = 32; off >= 1; off >>= 1) ss += __shfl_xor(ss, off);
            v = (v - m) - logf(ss);
        }
        if (RELU) v = fmaxf(v, 0.f);
        Out[(size_t)wid * 64 + lane] = v;
    }
}

// ---------------------------------------------------------------- launch

extern "C" void kernel_launch(void* const* d_in, const int* in_sizes, int n_in,
                              void* d_out, int out_size, void* d_ws, size_t ws_size,
                              hipStream_t stream) {
    const float* features = (const float*)d_in[0];
    const int*   src      = (const int*)d_in[1];
    const int*   dst      = (const int*)d_in[2];
    const float* W1       = (const float*)d_in[3];
    const float* b1       = (const float*)d_in[4];
    const float* W2       = (const float*)d_in[5];
    const float* b2       = (const float*)d_in[6];
    const float* W3       = (const float*)d_in[7];
    const float* b3       = (const float*)d_in[8];
    float*       out      = (float*)d_out;

    const int N = in_sizes[0] / IN_C;   // 100000
    const int E = in_sizes[1];          // 1600000

    char* ws = (char*)d_ws;
    const size_t SLOT = 400128;                         // >= (N+1)*4, 128B-aligned
    int*   cnt_out   = (int*)(ws + 0 * SLOT);
    int*   cnt_in    = (int*)(ws + 1 * SLOT);
    int*   row_start = (int*)(ws + 2 * SLOT);
    int*   cursor    = (int*)(ws + 3 * SLOT);
    float* iso       = (float*)(ws + 4 * SLOT);
    float* isi       = (float*)(ws + 5 * SLOT);
    int*   csr       = (int*)(ws + 6 * SLOT);                           // E ints
    u16*   Hb        = (u16*)(ws + 6 * SLOT + 6400000);                 // N*128 bf16 (25.6MB slot)
    float* act       = (float*)(ws + 6 * SLOT + 6400000 + 51200000);    // N*128 f32
    int*   blocksum  = (int*)(ws + 6 * SLOT + 6400000 + 2 * 51200000);  // 128 ints
    int*   blockoff  = blocksum + 128;                                  // 128 ints

    // ---- CSR build (per-launch, deterministic work) ----
    const int zn = 2 * (int)(SLOT / 4);
    const int nb = (N + 1023) / 1024;   // scan blocks (98 for N=100000, <=128)
    zero_kernel<<<(zn + 255) / 256, 256, 0, stream>>>(cnt_out, zn);
    degree_kernel<<<1024, 256, 0, stream>>>(src, dst, cnt_out, cnt_in, E);
    scan_pass1<<<nb, 256, 0, stream>>>(cnt_in, blocksum, N);
    scan_pass2<<<1, 128, 0, stream>>>(blocksum, blockoff, row_start, N, nb);
    scan_pass3<<<nb, 256, 0, stream>>>(cnt_in, cnt_out, blockoff, row_start, cursor, iso, isi, N);
    fill_kernel<<<1024, 256, 0, stream>>>(src, dst, cursor, csr, E);

    // ---- 3-layer GCN ----
    const int gblocks = (N + 127) / 128;
    const size_t lds128 = (size_t)(128 * 128 + 128 * 130) * sizeof(float); // 129 KiB
    const size_t lds64  = (size_t)(128 * 64  + 128 * 130) * sizeof(float); //  97 KiB
    const int ablocks = (int)(((size_t)N * 64 + 255) / 256);

    // layer 1
    gemm_kernel<128><<<gblocks, 256, lds128, stream>>>(features, W1, iso, Hb, N);
    agg_kernel<128, true, false><<<ablocks, 256, 0, stream>>>(Hb, row_start, csr, isi, b1, act, N);
    // layer 2
    gemm_kernel<128><<<gblocks, 256, lds128, stream>>>(act, W2, iso, Hb, N);
    agg_kernel<128, true, false><<<ablocks, 256, 0, stream>>>(Hb, row_start, csr, isi, b2, act, N);
    // layer 3 + fused log_softmax
    gemm_kernel<64><<<gblocks, 256, lds64, stream>>>(act, W3, iso, Hb, N);
    agg_kernel<64, false, true><<<ablocks, 256, 0, stream>>>(Hb, row_start, csr, isi, b3, out, N);
}

// Round 4
// 720.880 us; speedup vs baseline: 2.0462x; 1.3933x over previous
//
#include <hip/hip_runtime.h>
#include <hip/hip_bf16.h>

#define IN_C 128
#define HID_C 128
#define OUT_C 64

typedef unsigned short u16;
typedef unsigned int   u32;

// ---------------------------------------------------------------- utilities

__global__ void zero_kernel(int* __restrict__ p, int n) {
    int i = blockIdx.x * blockDim.x + threadIdx.x;
    if (i < n) p[i] = 0;
}

// histogram of src (out-degree) and dst (in-degree)
__global__ void degree_kernel(const int* __restrict__ src, const int* __restrict__ dst,
                              int* __restrict__ cnt_out, int* __restrict__ cnt_in, int E) {
    for (int i = blockIdx.x * blockDim.x + threadIdx.x; i < E; i += gridDim.x * blockDim.x) {
        atomicAdd(&cnt_out[src[i]], 1);
        atomicAdd(&cnt_in[dst[i]], 1);
    }
}

// ---- device-wide exclusive scan of cnt_in (3 passes, 1024 elems/block) ----

__global__ __launch_bounds__(256)
void scan_pass1(const int* __restrict__ cnt_in, int* __restrict__ blocksum, int N) {
    const int b = blockIdx.x, t = threadIdx.x;
    const int base = b * 1024 + t * 4;
    int s = 0;
#pragma unroll
    for (int j = 0; j < 4; ++j) {
        int idx = base + j;
        if (idx < N) s += cnt_in[idx];
    }
#pragma unroll
    for (int off = 32; off >= 1; off >>= 1) s += __shfl_xor(s, off);
    __shared__ int wsum[4];
    if ((t & 63) == 0) wsum[t >> 6] = s;
    __syncthreads();
    if (t == 0) blocksum[b] = wsum[0] + wsum[1] + wsum[2] + wsum[3];
}

// single small block scans the (<=128) block sums
__global__ __launch_bounds__(128)
void scan_pass2(const int* __restrict__ blocksum, int* __restrict__ blockoff,
                int* __restrict__ row_start, int N, int nb) {
    __shared__ int s[128];
    const int t = threadIdx.x;
    int v = (t < nb) ? blocksum[t] : 0;
    s[t] = v;
    __syncthreads();
    for (int off = 1; off < 128; off <<= 1) {
        int x = (t >= off) ? s[t - off] : 0;
        __syncthreads();
        s[t] += x;
        __syncthreads();
    }
    if (t < nb) blockoff[t] = s[t] - v;     // exclusive
    if (t == 127) row_start[N] = s[127];    // total (=E)
}

__global__ __launch_bounds__(256)
void scan_pass3(const int* __restrict__ cnt_in, const int* __restrict__ cnt_out,
                const int* __restrict__ blockoff,
                int* __restrict__ row_start, int* __restrict__ cursor,
                float* __restrict__ iso, float* __restrict__ isi, int N) {
    __shared__ int ssum[256];
    const int b = blockIdx.x, t = threadIdx.x;
    const int base = b * 1024 + t * 4;
    int c[4];
#pragma unroll
    for (int j = 0; j < 4; ++j) {
        int idx = base + j;
        c[j] = (idx < N) ? cnt_in[idx] : 0;
    }
    const int tot = c[0] + c[1] + c[2] + c[3];
    ssum[t] = tot;
    __syncthreads();
    for (int off = 1; off < 256; off <<= 1) {
        int v = (t >= off) ? ssum[t - off] : 0;
        __syncthreads();
        ssum[t] += v;
        __syncthreads();
    }
    int run = blockoff[b] + ssum[t] - tot;  // exclusive prefix for this thread
#pragma unroll
    for (int j = 0; j < 4; ++j) {
        int idx = base + j;
        if (idx < N) {
            row_start[idx] = run;
            cursor[idx]    = run;
            run += c[j];
            int di = c[j] < 1 ? 1 : c[j];
            int co = cnt_out[idx];
            int dd = co < 1 ? 1 : co;
            isi[idx] = rsqrtf((float)di);
            iso[idx] = rsqrtf((float)dd);
        }
    }
}

// bucket edges by dst: csr_src[row_start[dst]..] = src
__global__ void fill_kernel(const int* __restrict__ src, const int* __restrict__ dst,
                            int* __restrict__ cursor, int* __restrict__ csr_src, int E) {
    for (int i = blockIdx.x * blockDim.x + threadIdx.x; i < E; i += gridDim.x * blockDim.x) {
        int p = atomicAdd(&cursor[dst[i]], 1);
        csr_src[p] = src[i];
    }
}

// ---------------------------------------------------------------- GEMM
// H[N x C] (bf16) = (X[N x 128] * iso[:,None]) @ W[128 x C]
// tile: 128 rows x C cols, whole K=128. W + padded-X staged in dynamic LDS.
template <int C>
__global__ __launch_bounds__(256)
void gemm_kernel(const float* __restrict__ X, const float* __restrict__ W,
                 const float* __restrict__ iso, u16* __restrict__ H, int N) {
    extern __shared__ float lds[];
    float* Ws = lds;               // 128*C
    float* Xs = lds + 128 * C;     // 128 rows * PAD
    const int PAD = 130;           // rows 8 apart -> +16 banks (2-way, free)
    const int t = threadIdx.x;
    const int row0 = blockIdx.x * 128;

    // stage W
    for (int i = t * 4; i < 128 * C; i += 256 * 4) {
        *(float4*)(Ws + i) = *(const float4*)(W + i);
    }
    // stage X, scaled by iso (128 rows x 32 float4-chunks)
    for (int i = t; i < 128 * 32; i += 256) {
        int r  = i >> 5;
        int kv = (i & 31) << 2;
        int gr = row0 + r;
        if (gr >= N) gr = N - 1;           // clamp (dup row, never stored)
        float sc = iso[gr];
        float4 x = *(const float4*)(X + (size_t)gr * 128 + kv);
        float* d = Xs + r * PAD + kv;
        d[0] = x.x * sc; d[1] = x.y * sc; d[2] = x.z * sc; d[3] = x.w * sc;
    }
    __syncthreads();

    const int CPT = C / 16;                // cols per thread: 8 (C=128) or 4 (C=64)
    const int tc = t & 15, tr = t >> 4;
    const int r0 = tr * 8, c0 = tc * CPT;

    float acc[8][CPT];
#pragma unroll
    for (int i = 0; i < 8; ++i)
#pragma unroll
        for (int j = 0; j < CPT; ++j) acc[i][j] = 0.f;

    for (int k = 0; k < 128; ++k) {
        float a[8];
#pragma unroll
        for (int i = 0; i < 8; ++i) a[i] = Xs[(r0 + i) * PAD + k];
        float b[CPT];
#pragma unroll
        for (int j = 0; j < CPT; ++j) b[j] = Ws[k * C + c0 + j];
#pragma unroll
        for (int i = 0; i < 8; ++i)
#pragma unroll
            for (int j = 0; j < CPT; ++j) acc[i][j] = fmaf(a[i], b[j], acc[i][j]);
    }

#pragma unroll
    for (int i = 0; i < 8; ++i) {
        int gr = row0 + r0 + i;
        if (gr < N) {
            alignas(16) u16 u[CPT];
#pragma unroll
            for (int j = 0; j < CPT; ++j) {
                __hip_bfloat16 h = __float2bfloat16(acc[i][j]);   // RNE
                u[j] = *(u16*)&h;
            }
            if (CPT == 8) {
                *(uint4*)(H + (size_t)gr * C + c0) = *(uint4*)u;
            } else {
                *(uint2*)(H + (size_t)gr * C + c0) = *(uint2*)u;
            }
        }
    }
}

// ---------------------------------------------------------------- aggregation
// one wave per node: out[v] = (sum_{e in CSR[v]} Hbf16[src[e]]) * isi[v] + bias
// Edge indices are chunk-prefetched (one coalesced load per 64 edges) and
// broadcast via readlane (SGPR row base); rows are gathered 4-at-a-time for MLP.
template <int C, bool RELU, bool FINAL>
__global__ __launch_bounds__(256)
void agg_kernel(const u16* __restrict__ H, const int* __restrict__ row_start,
                const int* __restrict__ csr_src, const float* __restrict__ isi,
                const float* __restrict__ bias, float* __restrict__ Out, int N) {
    const int wid  = (int)((blockIdx.x * (size_t)blockDim.x + threadIdx.x) >> 6);
    const int lane = threadIdx.x & 63;
    if (wid >= N) return;
    const int rs = row_start[wid];
    const int re = row_start[wid + 1];
    const float sc = isi[wid];

    if (C == 128) {
        float ax = 0.f, ay = 0.f;
        int e = rs;
        while (e < re) {
            int nloc = re - e;
            if (nloc > 64) nloc = 64;
            int idx = 0;
            if (lane < nloc) idx = csr_src[e + lane];
            int j = 0;
            for (; j + 4 <= nloc; j += 4) {
                int s0 = __builtin_amdgcn_readlane(idx, j);
                int s1 = __builtin_amdgcn_readlane(idx, j + 1);
                int s2 = __builtin_amdgcn_readlane(idx, j + 2);
                int s3 = __builtin_amdgcn_readlane(idx, j + 3);
                u32 v0 = *(const u32*)(H + (size_t)s0 * 128 + lane * 2);
                u32 v1 = *(const u32*)(H + (size_t)s1 * 128 + lane * 2);
                u32 v2 = *(const u32*)(H + (size_t)s2 * 128 + lane * 2);
                u32 v3 = *(const u32*)(H + (size_t)s3 * 128 + lane * 2);
                ax += __uint_as_float(v0 << 16); ay += __uint_as_float(v0 & 0xffff0000u);
                ax += __uint_as_float(v1 << 16); ay += __uint_as_float(v1 & 0xffff0000u);
                ax += __uint_as_float(v2 << 16); ay += __uint_as_float(v2 & 0xffff0000u);
                ax += __uint_as_float(v3 << 16); ay += __uint_as_float(v3 & 0xffff0000u);
            }
            for (; j < nloc; ++j) {
                int s0 = __builtin_amdgcn_readlane(idx, j);
                u32 v0 = *(const u32*)(H + (size_t)s0 * 128 + lane * 2);
                ax += __uint_as_float(v0 << 16); ay += __uint_as_float(v0 & 0xffff0000u);
            }
            e += nloc;
        }
        float2 b = *(const float2*)(bias + lane * 2);
        float o0 = ax * sc + b.x;
        float o1 = ay * sc + b.y;
        if (RELU) { o0 = fmaxf(o0, 0.f); o1 = fmaxf(o1, 0.f); }
        float2 o = make_float2(o0, o1);
        *(float2*)(Out + (size_t)wid * 128 + lane * 2) = o;
    } else {
        float a = 0.f;
        int e = rs;
        while (e < re) {
            int nloc = re - e;
            if (nloc > 64) nloc = 64;
            int idx = 0;
            if (lane < nloc) idx = csr_src[e + lane];
            int j = 0;
            for (; j + 4 <= nloc; j += 4) {
                int s0 = __builtin_amdgcn_readlane(idx, j);
                int s1 = __builtin_amdgcn_readlane(idx, j + 1);
                int s2 = __builtin_amdgcn_readlane(idx, j + 2);
                int s3 = __builtin_amdgcn_readlane(idx, j + 3);
                u32 v0 = H[(size_t)s0 * 64 + lane];
                u32 v1 = H[(size_t)s1 * 64 + lane];
                u32 v2 = H[(size_t)s2 * 64 + lane];
                u32 v3 = H[(size_t)s3 * 64 + lane];
                a += __uint_as_float(v0 << 16);
                a += __uint_as_float(v1 << 16);
                a += __uint_as_float(v2 << 16);
                a += __uint_as_float(v3 << 16);
            }
            for (; j < nloc; ++j) {
                int s0 = __builtin_amdgcn_readlane(idx, j);
                a += __uint_as_float((u32)H[(size_t)s0 * 64 + lane] << 16);
            }
            e += nloc;
        }
        float v = a * sc + bias[lane];
        if (FINAL) {
            float m = v;
#pragma unroll
            for (int off = 32; off >= 1; off >>= 1) m = fmaxf(m, __shfl_xor(m, off));
            float ex = expf(v - m);
            float ss = ex;
#pragma unroll
            for (int off = 32; off >= 1; off >>= 1) ss += __shfl_xor(ss, off);
            v = (v - m) - logf(ss);
        }
        if (RELU) v = fmaxf(v, 0.f);
        Out[(size_t)wid * 64 + lane] = v;
    }
}

// ---------------------------------------------------------------- launch

extern "C" void kernel_launch(void* const* d_in, const int* in_sizes, int n_in,
                              void* d_out, int out_size, void* d_ws, size_t ws_size,
                              hipStream_t stream) {
    const float* features = (const float*)d_in[0];
    const int*   src      = (const int*)d_in[1];
    const int*   dst      = (const int*)d_in[2];
    const float* W1       = (const float*)d_in[3];
    const float* b1       = (const float*)d_in[4];
    const float* W2       = (const float*)d_in[5];
    const float* b2       = (const float*)d_in[6];
    const float* W3       = (const float*)d_in[7];
    const float* b3       = (const float*)d_in[8];
    float*       out      = (float*)d_out;

    const int N = in_sizes[0] / IN_C;   // 100000
    const int E = in_sizes[1];          // 1600000

    char* ws = (char*)d_ws;
    const size_t SLOT = 400128;                         // >= (N+1)*4, 128B-aligned
    int*   cnt_out   = (int*)(ws + 0 * SLOT);
    int*   cnt_in    = (int*)(ws + 1 * SLOT);
    int*   row_start = (int*)(ws + 2 * SLOT);
    int*   cursor    = (int*)(ws + 3 * SLOT);
    float* iso       = (float*)(ws + 4 * SLOT);
    float* isi       = (float*)(ws + 5 * SLOT);
    int*   csr       = (int*)(ws + 6 * SLOT);                           // E ints
    u16*   Hb        = (u16*)(ws + 6 * SLOT + 6400000);                 // N*128 bf16 (25.6MB slot)
    float* act       = (float*)(ws + 6 * SLOT + 6400000 + 51200000);    // N*128 f32
    int*   blocksum  = (int*)(ws + 6 * SLOT + 6400000 + 2 * 51200000);  // 128 ints
    int*   blockoff  = blocksum + 128;                                  // 128 ints

    // ---- CSR build (per-launch, deterministic work) ----
    const int zn = 2 * (int)(SLOT / 4);
    const int nb = (N + 1023) / 1024;   // scan blocks (98 for N=100000, <=128)
    zero_kernel<<<(zn + 255) / 256, 256, 0, stream>>>(cnt_out, zn);
    degree_kernel<<<1024, 256, 0, stream>>>(src, dst, cnt_out, cnt_in, E);
    scan_pass1<<<nb, 256, 0, stream>>>(cnt_in, blocksum, N);
    scan_pass2<<<1, 128, 0, stream>>>(blocksum, blockoff, row_start, N, nb);
    scan_pass3<<<nb, 256, 0, stream>>>(cnt_in, cnt_out, blockoff, row_start, cursor, iso, isi, N);
    fill_kernel<<<1024, 256, 0, stream>>>(src, dst, cursor, csr, E);

    // ---- 3-layer GCN ----
    const int gblocks = (N + 127) / 128;
    const size_t lds128 = (size_t)(128 * 128 + 128 * 130) * sizeof(float); // 129 KiB
    const size_t lds64  = (size_t)(128 * 64  + 128 * 130) * sizeof(float); //  97 KiB
    const int ablocks = (int)(((size_t)N * 64 + 255) / 256);

    // layer 1
    gemm_kernel<128><<<gblocks, 256, lds128, stream>>>(features, W1, iso, Hb, N);
    agg_kernel<128, true, false><<<ablocks, 256, 0, stream>>>(Hb, row_start, csr, isi, b1, act, N);
    // layer 2
    gemm_kernel<128><<<gblocks, 256, lds128, stream>>>(act, W2, iso, Hb, N);
    agg_kernel<128, true, false><<<ablocks, 256, 0, stream>>>(Hb, row_start, csr, isi, b2, act, N);
    // layer 3 + fused log_softmax
    gemm_kernel<64><<<gblocks, 256, lds64, stream>>>(act, W3, iso, Hb, N);
    agg_kernel<64, false, true><<<ablocks, 256, 0, stream>>>(Hb, row_start, csr, isi, b3, out, N);
}